// Round 3
// baseline (468.374 us; speedup 1.0000x reference)
//
#include <hip/hip_runtime.h>
#include <math.h>

#define BATCH 4
#define LSEQ 2048
#define BL (BATCH*LSEQ)        // 8192
#define DMODEL 256
#define DINNER 512
#define NSTATE 16
#define DTRANK 16
#define NPROJ 48               // DTRANK + 2*NSTATE
#define HORIZ 96
#define NCH 32                 // scan chunks
#define TCH (LSEQ/NCH)         // 64
#define KPSTRIDE (BL*NPROJ)    // 393216, part kp-stride in floats

// ================= kernel 1: x_in^T = W1 @ X^T (fp32, 128x128 tile, 8x8/thread) =================
__global__ __launch_bounds__(256) void k_inproj(const float* __restrict__ X,
                                                const float* __restrict__ W,
                                                float* __restrict__ xinT) {
  __shared__ float As[16][132];  // [k][j]
  __shared__ float Bs[16][132];  // [k][m]
  const int m0 = blockIdx.x * 128;
  const int j0 = blockIdx.y * 128;
  const int tid = threadIdx.x;
  const int lrow = tid >> 1;          // 0..127
  const int lk0  = (tid & 1) << 3;    // 0 or 8
  const int tj4  = (tid >> 4) << 2;   // 0..60
  const int tm4  = (tid & 15) << 2;   // 0..60
  const float* Arow = &W[(size_t)(j0 + lrow) * DMODEL + lk0];
  const float* Brow = &X[(size_t)(m0 + lrow) * DMODEL + lk0];
  float4 a0 = *(const float4*)(Arow);
  float4 a1 = *(const float4*)(Arow + 4);
  float4 b0 = *(const float4*)(Brow);
  float4 b1 = *(const float4*)(Brow + 4);
  float acc[8][8] = {};
  for (int k0 = 0; k0 < DMODEL; k0 += 16) {
    __syncthreads();
    As[lk0+0][lrow]=a0.x; As[lk0+1][lrow]=a0.y; As[lk0+2][lrow]=a0.z; As[lk0+3][lrow]=a0.w;
    As[lk0+4][lrow]=a1.x; As[lk0+5][lrow]=a1.y; As[lk0+6][lrow]=a1.z; As[lk0+7][lrow]=a1.w;
    Bs[lk0+0][lrow]=b0.x; Bs[lk0+1][lrow]=b0.y; Bs[lk0+2][lrow]=b0.z; Bs[lk0+3][lrow]=b0.w;
    Bs[lk0+4][lrow]=b1.x; Bs[lk0+5][lrow]=b1.y; Bs[lk0+6][lrow]=b1.z; Bs[lk0+7][lrow]=b1.w;
    __syncthreads();
    if (k0 + 16 < DMODEL) {
      a0 = *(const float4*)(Arow + k0 + 16);
      a1 = *(const float4*)(Arow + k0 + 20);
      b0 = *(const float4*)(Brow + k0 + 16);
      b1 = *(const float4*)(Brow + k0 + 20);
    }
    #pragma unroll
    for (int k = 0; k < 16; ++k) {
      float4 alo = *(const float4*)&As[k][tj4];
      float4 ahi = *(const float4*)&As[k][64 + tj4];
      float4 blo = *(const float4*)&Bs[k][tm4];
      float4 bhi = *(const float4*)&Bs[k][64 + tm4];
      float aj[8] = {alo.x,alo.y,alo.z,alo.w, ahi.x,ahi.y,ahi.z,ahi.w};
      float bm[8] = {blo.x,blo.y,blo.z,blo.w, bhi.x,bhi.y,bhi.z,bhi.w};
      #pragma unroll
      for (int i = 0; i < 8; ++i)
        #pragma unroll
        for (int j = 0; j < 8; ++j) acc[i][j] = fmaf(aj[i], bm[j], acc[i][j]);
    }
  }
  #pragma unroll
  for (int ii = 0; ii < 2; ++ii)
    #pragma unroll
    for (int i = 0; i < 4; ++i) {
      int j = j0 + ii * 64 + tj4 + i;
      int r = ii * 4 + i;
      float4 v0 = make_float4(acc[r][0], acc[r][1], acc[r][2], acc[r][3]);
      float4 v1 = make_float4(acc[r][4], acc[r][5], acc[r][6], acc[r][7]);
      *(float4*)&xinT[(size_t)j * BL + m0 + tm4] = v0;
      *(float4*)&xinT[(size_t)j * BL + m0 + 64 + tm4] = v1;
    }
}

// ================= kernel 2: conv+silu (registers) + uT + x_dbl partials =================
// grid (btc=128, kp=4); block 256. d-chunk = 128 channels, 64 tokens.
__global__ __launch_bounds__(256) void k_convdbl(const float* __restrict__ xinT,
                                                 const float* __restrict__ cw,
                                                 const float* __restrict__ cb,
                                                 const float* __restrict__ xpw,
                                                 float* __restrict__ uT,
                                                 float* __restrict__ part,
                                                 unsigned* __restrict__ cnt) {
  __shared__ float sw2[48][132];   // [o][k_local], 25.3 KB
  __shared__ float su[32][68];     // [k_sub][tok], 8.7 KB
  __shared__ float scw[128][4];
  __shared__ float scb[128];
  const int btc = blockIdx.x;
  const int kp  = blockIdx.y;
  const int tid = threadIdx.x;
  if (btc == 0 && kp == 0 && tid < 128) cnt[tid] = 0;  // zero scan counters
  const int bt0 = btc * 64;
  const int kbase = kp * 128;
  // stage x_proj weights, o-major rows (contiguous copies)
  for (int i = tid; i < 48 * 32; i += 256) {
    int o = i >> 5, k4 = (i & 31) << 2;
    *(float4*)&sw2[o][k4] = *(const float4*)&xpw[(size_t)o * DINNER + kbase + k4];
  }
  if (tid < 128) {
    *(float4*)&scw[tid][0] = *(const float4*)&cw[(kbase + tid) * 4];
    scb[tid] = cb[kbase + tid];
  }
  const int t0 = (tid & 15) << 2;
  const int o0 = (tid >> 4) * 3;
  const bool edge0 = ((bt0 & (LSEQ - 1)) == 0);
  float acc[4][3] = {};
  for (int ks = 0; ks < 4; ++ks) {
    __syncthreads();  // su free (and weights staged, first iter)
    {
      int r  = tid >> 3;           // 0..31
      int c8 = (tid & 7) << 3;     // 0..56
      int dloc = ks * 32 + r;
      int d = kbase + dloc;
      const float* xr = &xinT[(size_t)d * BL + bt0 + c8];
      float4 v0 = *(const float4*)xr;
      float4 v1 = *(const float4*)(xr + 4);
      bool edge = edge0 && (c8 == 0);
      float xm3 = edge ? 0.f : xr[-3];
      float xm2 = edge ? 0.f : xr[-2];
      float xm1 = edge ? 0.f : xr[-1];
      float xv[11] = {xm3, xm2, xm1, v0.x, v0.y, v0.z, v0.w, v1.x, v1.y, v1.z, v1.w};
      float w0 = scw[dloc][0], w1 = scw[dloc][1], w2 = scw[dloc][2], w3 = scw[dloc][3];
      float bias = scb[dloc];
      float uu[8];
      #pragma unroll
      for (int c = 0; c < 8; ++c) {
        float s = bias;
        s = fmaf(w0, xv[c],     s);
        s = fmaf(w1, xv[c + 1], s);
        s = fmaf(w2, xv[c + 2], s);
        s = fmaf(w3, xv[c + 3], s);
        uu[c] = s / (1.f + __expf(-s));
      }
      *(float4*)&su[r][c8]     = make_float4(uu[0], uu[1], uu[2], uu[3]);
      *(float4*)&su[r][c8 + 4] = make_float4(uu[4], uu[5], uu[6], uu[7]);
      *(float4*)&uT[(size_t)d * BL + bt0 + c8]     = make_float4(uu[0], uu[1], uu[2], uu[3]);
      *(float4*)&uT[(size_t)d * BL + bt0 + c8 + 4] = make_float4(uu[4], uu[5], uu[6], uu[7]);
    }
    __syncthreads();
    #pragma unroll 4
    for (int kk = 0; kk < 32; ++kk) {
      float4 uv = *(const float4*)&su[kk][t0];
      float uu[4] = {uv.x, uv.y, uv.z, uv.w};
      int kcol = ks * 32 + kk;
      float ww[3] = {sw2[o0][kcol], sw2[o0 + 1][kcol], sw2[o0 + 2][kcol]};
      #pragma unroll
      for (int i = 0; i < 4; ++i)
        #pragma unroll
        for (int j = 0; j < 3; ++j) acc[i][j] = fmaf(uu[i], ww[j], acc[i][j]);
    }
  }
  #pragma unroll
  for (int i = 0; i < 4; ++i)
    #pragma unroll
    for (int j = 0; j < 3; ++j)
      part[(size_t)kp * KPSTRIDE + (size_t)(bt0 + t0 + i) * NPROJ + o0 + j] = acc[i][j];
}

// ================= kernel 3: reduce+delta (LDS prologue) + chunked scan + last-block combine =================
// grid (dblk=32, c=32, b=4); block 256 = 16 d x 16 n.
__global__ __launch_bounds__(256) void k_scan(const float* __restrict__ uT,
                                              const float* __restrict__ part,
                                              const float* __restrict__ dtw,
                                              const float* __restrict__ dtb,
                                              const float* __restrict__ Alog,
                                              const float* __restrict__ Dp,
                                              float* __restrict__ aprod,
                                              float* __restrict__ hacc,
                                              unsigned* __restrict__ cnt,
                                              float* __restrict__ ybuf) {
  __shared__ float sdt[64][16];
  __shared__ float sB[64][16];
  __shared__ float sdelta[64][16];   // [tok][dl]
  __shared__ float sdtw[16][17];
  __shared__ float sdtb[16];
  __shared__ unsigned sflag;
  const int dblk = blockIdx.x;
  const int c    = blockIdx.y;
  const int b    = blockIdx.z;
  const int tid  = threadIdx.x;
  const int bt0  = b * LSEQ + c * TCH;
  // reduce dt & B partials for this token chunk
  for (int i = tid; i < 1024; i += 256) {
    int tok = i >> 4, o = i & 15;
    size_t base = (size_t)(bt0 + tok) * NPROJ + o;
    sdt[tok][o] = part[base] + part[base + KPSTRIDE] + part[base + 2 * KPSTRIDE] + part[base + 3 * KPSTRIDE];
    size_t bb = base + DTRANK;
    sB[tok][o] = part[bb] + part[bb + KPSTRIDE] + part[bb + 2 * KPSTRIDE] + part[bb + 3 * KPSTRIDE];
  }
  {
    int dl = tid >> 4, r = tid & 15;
    sdtw[dl][r] = dtw[(dblk * 16 + dl) * DTRANK + r];
    if (tid < 16) sdtb[tid] = dtb[dblk * 16 + tid];
  }
  __syncthreads();
  // delta = softplus(dt @ dtw^T + dtb) for [64 tok][16 dl]
  for (int i = tid; i < 1024; i += 256) {
    int tok = i >> 4, dl = i & 15;
    float a = sdtb[dl];
    #pragma unroll
    for (int r = 0; r < DTRANK; ++r) a = fmaf(sdt[tok][r], sdtw[dl][r], a);
    sdelta[tok][dl] = (a > 20.f) ? a : log1pf(__expf(a));
  }
  __syncthreads();
  const int dl = tid >> 4, n = tid & 15;
  const int d = dblk * 16 + dl;
  const float A = -__expf(Alog[d * NSTATE + n]);
  float ap = 1.f, h = 0.f;
  const float* ur = &uT[(size_t)d * BL + bt0];
  for (int tt = 0; tt < TCH; ++tt) {
    float dlt = sdelta[tt][dl];
    float dA = __expf(dlt * A);
    h = fmaf(dA, h, dlt * sB[tt][n] * ur[tt]);
    ap *= dA;
  }
  size_t off = (((size_t)b * NCH + c) * DINNER + d) * NSTATE + n;
  aprod[off] = ap;
  hacc[off]  = h;
  __threadfence();
  if (tid == 0) sflag = atomicAdd(&cnt[b * 32 + dblk], 1u);
  __syncthreads();
  if (sflag == 31) {           // last block for (b, dblk): combine + y
    __threadfence();
    float hh = 0.f;
    for (int cc = 0; cc < NCH; ++cc) {
      size_t o2 = (((size_t)b * NCH + cc) * DINNER + d) * NSTATE + n;
      hh = fmaf(aprod[o2], hh, hacc[o2]);
    }
    const int btL = b * LSEQ + LSEQ - 1;
    size_t cbase = (size_t)btL * NPROJ + DTRANK + NSTATE + n;
    float Cv = part[cbase] + part[cbase + KPSTRIDE] + part[cbase + 2 * KPSTRIDE] + part[cbase + 3 * KPSTRIDE];
    float v = hh * Cv;
    v += __shfl_xor(v, 1);
    v += __shfl_xor(v, 2);
    v += __shfl_xor(v, 4);
    v += __shfl_xor(v, 8);
    if (n == 0) {
      float y = v + uT[(size_t)d * BL + btL] * Dp[d];
      ybuf[b * DINNER + d] = y;   // raw y (silu(z) gate applied in k_head)
    }
  }
}

// ================= kernel 4: z(last) + gate + out_proj + head =================
__global__ __launch_bounds__(256) void k_head(const float* __restrict__ X,
                                              const float* __restrict__ ipw,
                                              const float* __restrict__ ybuf,
                                              const float* __restrict__ opw,
                                              const float* __restrict__ hw,
                                              const float* __restrict__ hb,
                                              float* __restrict__ out) {
  __shared__ float sx[DMODEL];
  __shared__ float sy[DINNER];
  __shared__ float ov[DMODEL];
  const int b = blockIdx.x, tid = threadIdx.x;
  sx[tid] = X[((size_t)b * LSEQ + LSEQ - 1) * DMODEL + tid];
  __syncthreads();
  #pragma unroll
  for (int rr = 0; rr < 2; ++rr) {
    int j = tid + rr * 256;
    const float* wr = &ipw[(size_t)(DINNER + j) * DMODEL];
    float z = 0.f;
    #pragma unroll 4
    for (int k = 0; k < DMODEL; k += 4) {
      float4 w4 = *(const float4*)&wr[k];
      float4 x4 = *(const float4*)&sx[k];
      z = fmaf(w4.x, x4.x, z); z = fmaf(w4.y, x4.y, z);
      z = fmaf(w4.z, x4.z, z); z = fmaf(w4.w, x4.w, z);
    }
    float yv = ybuf[b * DINNER + j];
    sy[j] = yv * z / (1.f + __expf(-z));
  }
  __syncthreads();
  {
    float s = 0.f;
    const float* wr = &opw[(size_t)tid * DINNER];
    #pragma unroll 4
    for (int k = 0; k < DINNER; k += 4) {
      float4 w4 = *(const float4*)&wr[k];
      float4 y4 = *(const float4*)&sy[k];
      s = fmaf(w4.x, y4.x, s); s = fmaf(w4.y, y4.y, s);
      s = fmaf(w4.z, y4.z, s); s = fmaf(w4.w, y4.w, s);
    }
    ov[tid] = s;
  }
  __syncthreads();
  if (tid < HORIZ) {
    float a = hb[tid];
    const float* hr = &hw[(size_t)tid * DMODEL];
    #pragma unroll 4
    for (int k = 0; k < DMODEL; k += 4) {
      float4 w4 = *(const float4*)&hr[k];
      float4 o4 = *(const float4*)&ov[k];
      a = fmaf(w4.x, o4.x, a); a = fmaf(w4.y, o4.y, a);
      a = fmaf(w4.z, o4.z, a); a = fmaf(w4.w, o4.w, a);
    }
    out[b * HORIZ + tid] = a;
  }
}

extern "C" void kernel_launch(void* const* d_in, const int* in_sizes, int n_in,
                              void* d_out, int out_size, void* d_ws, size_t ws_size,
                              hipStream_t stream) {
  (void)in_sizes; (void)n_in; (void)out_size; (void)ws_size;
  const float* x    = (const float*)d_in[0];
  const float* ipw  = (const float*)d_in[1];
  const float* cw   = (const float*)d_in[2];
  const float* cb   = (const float*)d_in[3];
  const float* xpw  = (const float*)d_in[4];
  const float* dtw  = (const float*)d_in[5];
  const float* dtb  = (const float*)d_in[6];
  const float* Alog = (const float*)d_in[7];
  const float* Dp   = (const float*)d_in[8];
  const float* opw  = (const float*)d_in[9];
  const float* hw   = (const float*)d_in[10];
  const float* hb   = (const float*)d_in[11];
  float* out = (float*)d_out;
  float* ws  = (float*)d_ws;

  // workspace layout (floats)
  float* xinT  = ws;                    // 4,194,304
  float* uT    = ws + 4194304;          // 4,194,304
  float* part  = ws + 8388608;          // 1,572,864
  float* aprod = ws + 9961472;          // 1,048,576
  float* hacc  = ws + 11010048;         // 1,048,576
  float* ybuf  = ws + 12058624;         //     2,048
  unsigned* cnt = (unsigned*)(ws + 12060672); // 128

  k_inproj<<<dim3(64, 4), 256, 0, stream>>>(x, ipw, xinT);
  k_convdbl<<<dim3(128, 4), 256, 0, stream>>>(xinT, cw, cb, xpw, uT, part, cnt);
  k_scan<<<dim3(32, NCH, BATCH), 256, 0, stream>>>(uT, part, dtw, dtb, Alog, Dp,
                                                   aprod, hacc, cnt, ybuf);
  k_head<<<BATCH, 256, 0, stream>>>(x, ipw, ybuf, opw, hw, hb, out);
}

// Round 4
// 190.832 us; speedup vs baseline: 2.4544x; 2.4544x over previous
//
#include <hip/hip_runtime.h>
#include <math.h>

#define BATCH 4
#define LSEQ 2048
#define BL (BATCH*LSEQ)        // 8192
#define DMODEL 256
#define DINNER 512
#define NSTATE 16
#define DTRANK 16
#define NPROJ 48               // DTRANK + 2*NSTATE
#define HORIZ 96
#define NCH 32                 // scan chunks
#define TCH (LSEQ/NCH)         // 64
#define KPSTRIDE (BL*NPROJ)    // 393216, part kp-stride in floats

// ================= kernel 1: x_in^T = W1 @ X^T (fp32, 128x128 tile, 8x8/thread) =================
__global__ __launch_bounds__(256) void k_inproj(const float* __restrict__ X,
                                                const float* __restrict__ W,
                                                float* __restrict__ xinT) {
  __shared__ float As[16][132];  // [k][j]
  __shared__ float Bs[16][132];  // [k][m]
  const int m0 = blockIdx.x * 128;
  const int j0 = blockIdx.y * 128;
  const int tid = threadIdx.x;
  const int lrow = tid >> 1;          // 0..127
  const int lk0  = (tid & 1) << 3;    // 0 or 8
  const int tj4  = (tid >> 4) << 2;   // 0..60
  const int tm4  = (tid & 15) << 2;   // 0..60
  const float* Arow = &W[(size_t)(j0 + lrow) * DMODEL + lk0];
  const float* Brow = &X[(size_t)(m0 + lrow) * DMODEL + lk0];
  float4 a0 = *(const float4*)(Arow);
  float4 a1 = *(const float4*)(Arow + 4);
  float4 b0 = *(const float4*)(Brow);
  float4 b1 = *(const float4*)(Brow + 4);
  float acc[8][8] = {};
  for (int k0 = 0; k0 < DMODEL; k0 += 16) {
    __syncthreads();
    As[lk0+0][lrow]=a0.x; As[lk0+1][lrow]=a0.y; As[lk0+2][lrow]=a0.z; As[lk0+3][lrow]=a0.w;
    As[lk0+4][lrow]=a1.x; As[lk0+5][lrow]=a1.y; As[lk0+6][lrow]=a1.z; As[lk0+7][lrow]=a1.w;
    Bs[lk0+0][lrow]=b0.x; Bs[lk0+1][lrow]=b0.y; Bs[lk0+2][lrow]=b0.z; Bs[lk0+3][lrow]=b0.w;
    Bs[lk0+4][lrow]=b1.x; Bs[lk0+5][lrow]=b1.y; Bs[lk0+6][lrow]=b1.z; Bs[lk0+7][lrow]=b1.w;
    __syncthreads();
    if (k0 + 16 < DMODEL) {
      a0 = *(const float4*)(Arow + k0 + 16);
      a1 = *(const float4*)(Arow + k0 + 20);
      b0 = *(const float4*)(Brow + k0 + 16);
      b1 = *(const float4*)(Brow + k0 + 20);
    }
    #pragma unroll
    for (int k = 0; k < 16; ++k) {
      float4 alo = *(const float4*)&As[k][tj4];
      float4 ahi = *(const float4*)&As[k][64 + tj4];
      float4 blo = *(const float4*)&Bs[k][tm4];
      float4 bhi = *(const float4*)&Bs[k][64 + tm4];
      float aj[8] = {alo.x,alo.y,alo.z,alo.w, ahi.x,ahi.y,ahi.z,ahi.w};
      float bm[8] = {blo.x,blo.y,blo.z,blo.w, bhi.x,bhi.y,bhi.z,bhi.w};
      #pragma unroll
      for (int i = 0; i < 8; ++i)
        #pragma unroll
        for (int j = 0; j < 8; ++j) acc[i][j] = fmaf(aj[i], bm[j], acc[i][j]);
    }
  }
  #pragma unroll
  for (int ii = 0; ii < 2; ++ii)
    #pragma unroll
    for (int i = 0; i < 4; ++i) {
      int j = j0 + ii * 64 + tj4 + i;
      int r = ii * 4 + i;
      float4 v0 = make_float4(acc[r][0], acc[r][1], acc[r][2], acc[r][3]);
      float4 v1 = make_float4(acc[r][4], acc[r][5], acc[r][6], acc[r][7]);
      *(float4*)&xinT[(size_t)j * BL + m0 + tm4] = v0;
      *(float4*)&xinT[(size_t)j * BL + m0 + 64 + tm4] = v1;
    }
}

// ================= kernel 2: conv+silu (registers) + uT + x_dbl partials =================
__global__ __launch_bounds__(256) void k_convdbl(const float* __restrict__ xinT,
                                                 const float* __restrict__ cw,
                                                 const float* __restrict__ cb,
                                                 const float* __restrict__ xpw,
                                                 float* __restrict__ uT,
                                                 float* __restrict__ part) {
  __shared__ float sw2[48][132];   // [o][k_local]
  __shared__ float su[32][68];     // [k_sub][tok]
  __shared__ float scw[128][4];
  __shared__ float scb[128];
  const int btc = blockIdx.x;
  const int kp  = blockIdx.y;
  const int tid = threadIdx.x;
  const int bt0 = btc * 64;
  const int kbase = kp * 128;
  for (int i = tid; i < 48 * 32; i += 256) {
    int o = i >> 5, k4 = (i & 31) << 2;
    *(float4*)&sw2[o][k4] = *(const float4*)&xpw[(size_t)o * DINNER + kbase + k4];
  }
  if (tid < 128) {
    *(float4*)&scw[tid][0] = *(const float4*)&cw[(kbase + tid) * 4];
    scb[tid] = cb[kbase + tid];
  }
  const int t0 = (tid & 15) << 2;
  const int o0 = (tid >> 4) * 3;
  const bool edge0 = ((bt0 & (LSEQ - 1)) == 0);
  float acc[4][3] = {};
  for (int ks = 0; ks < 4; ++ks) {
    __syncthreads();
    {
      int r  = tid >> 3;           // 0..31
      int c8 = (tid & 7) << 3;     // 0..56
      int dloc = ks * 32 + r;
      int d = kbase + dloc;
      const float* xr = &xinT[(size_t)d * BL + bt0 + c8];
      float4 v0 = *(const float4*)xr;
      float4 v1 = *(const float4*)(xr + 4);
      bool edge = edge0 && (c8 == 0);
      float xm3 = edge ? 0.f : xr[-3];
      float xm2 = edge ? 0.f : xr[-2];
      float xm1 = edge ? 0.f : xr[-1];
      float xv[11] = {xm3, xm2, xm1, v0.x, v0.y, v0.z, v0.w, v1.x, v1.y, v1.z, v1.w};
      float w0 = scw[dloc][0], w1 = scw[dloc][1], w2 = scw[dloc][2], w3 = scw[dloc][3];
      float bias = scb[dloc];
      float uu[8];
      #pragma unroll
      for (int c = 0; c < 8; ++c) {
        float s = bias;
        s = fmaf(w0, xv[c],     s);
        s = fmaf(w1, xv[c + 1], s);
        s = fmaf(w2, xv[c + 2], s);
        s = fmaf(w3, xv[c + 3], s);
        uu[c] = s / (1.f + __expf(-s));
      }
      *(float4*)&su[r][c8]     = make_float4(uu[0], uu[1], uu[2], uu[3]);
      *(float4*)&su[r][c8 + 4] = make_float4(uu[4], uu[5], uu[6], uu[7]);
      *(float4*)&uT[(size_t)d * BL + bt0 + c8]     = make_float4(uu[0], uu[1], uu[2], uu[3]);
      *(float4*)&uT[(size_t)d * BL + bt0 + c8 + 4] = make_float4(uu[4], uu[5], uu[6], uu[7]);
    }
    __syncthreads();
    #pragma unroll 4
    for (int kk = 0; kk < 32; ++kk) {
      float4 uv = *(const float4*)&su[kk][t0];
      float uu[4] = {uv.x, uv.y, uv.z, uv.w};
      int kcol = ks * 32 + kk;
      float ww[3] = {sw2[o0][kcol], sw2[o0 + 1][kcol], sw2[o0 + 2][kcol]};
      #pragma unroll
      for (int i = 0; i < 4; ++i)
        #pragma unroll
        for (int j = 0; j < 3; ++j) acc[i][j] = fmaf(uu[i], ww[j], acc[i][j]);
    }
  }
  #pragma unroll
  for (int i = 0; i < 4; ++i)
    #pragma unroll
    for (int j = 0; j < 3; ++j)
      part[(size_t)kp * KPSTRIDE + (size_t)(bt0 + t0 + i) * NPROJ + o0 + j] = acc[i][j];
}

// ================= kernel 3: single-pass scan: reduce+delta prologue per chunk, h in regs =================
// grid (dblk=32, b=4); block 256 = 16 d x 16 n. No cross-block communication.
__global__ __launch_bounds__(256) void k_scan(const float* __restrict__ uT,
                                              const float* __restrict__ part,
                                              const float* __restrict__ dtw,
                                              const float* __restrict__ dtb,
                                              const float* __restrict__ Alog,
                                              const float* __restrict__ Dp,
                                              float* __restrict__ ybuf) {
  __shared__ float sdt[64][16];      // [tok][r] dt_raw reduced
  __shared__ float sB[64][16];       // [tok][n] B reduced
  __shared__ float sdp[16][65][2];   // [dl][tok][{delta, delta*u}]
  __shared__ float su[16][68];       // [dl][tok]
  __shared__ float sdtw[16][17];
  __shared__ float sdtb[16];
  const int dblk = blockIdx.x;
  const int b    = blockIdx.y;
  const int tid  = threadIdx.x;
  const int d0 = dblk * 16;
  const int dl = tid >> 4, n = tid & 15;
  const int d = d0 + dl;
  sdtw[tid >> 4][tid & 15] = dtw[(d0 + (tid >> 4)) * DTRANK + (tid & 15)];
  if (tid < 16) sdtb[tid] = dtb[d0 + tid];
  const float A = -__expf(Alog[d * NSTATE + n]);
  const int ptok = tid >> 3;   // 0..31 (within r-half)
  const int poq  = tid & 7;    // float4 quad 0..7 -> o 0..31
  float4 pf[4][2];
  float4 uf;
  auto prefetch = [&](int c) {
    const int bt0 = b * LSEQ + c * TCH;
    #pragma unroll
    for (int kp = 0; kp < 4; ++kp)
      #pragma unroll
      for (int r = 0; r < 2; ++r) {
        int tok = r * 32 + ptok;
        pf[kp][r] = *(const float4*)&part[(size_t)kp * KPSTRIDE + (size_t)(bt0 + tok) * NPROJ + (poq << 2)];
      }
    uf = *(const float4*)&uT[(size_t)(d0 + (tid >> 4)) * BL + bt0 + ((tid & 15) << 2)];
  };
  prefetch(0);
  float h = 0.f;
  for (int c = 0; c < NCH; ++c) {
    __syncthreads();   // previous chunk's compute done; LDS reusable
    #pragma unroll
    for (int r = 0; r < 2; ++r) {
      float4 s = make_float4(pf[0][r].x + pf[1][r].x + pf[2][r].x + pf[3][r].x,
                             pf[0][r].y + pf[1][r].y + pf[2][r].y + pf[3][r].y,
                             pf[0][r].z + pf[1][r].z + pf[2][r].z + pf[3][r].z,
                             pf[0][r].w + pf[1][r].w + pf[2][r].w + pf[3][r].w);
      int tok = r * 32 + ptok;
      if (poq < 4) *(float4*)&sdt[tok][poq << 2] = s;
      else         *(float4*)&sB[tok][(poq - 4) << 2] = s;
    }
    *(float4*)&su[tid >> 4][(tid & 15) << 2] = uf;
    __syncthreads();
    if (c + 1 < NCH) prefetch(c + 1);   // overlap with delta compute
    #pragma unroll
    for (int p = 0; p < 4; ++p) {
      int i = tid + p * 256;
      int tok = i >> 4, ddl = i & 15;
      float a = sdtb[ddl];
      #pragma unroll
      for (int r = 0; r < DTRANK; ++r) a = fmaf(sdt[tok][r], sdtw[ddl][r], a);
      float dlt = (a > 20.f) ? a : log1pf(__expf(a));
      sdp[ddl][tok][0] = dlt;
      sdp[ddl][tok][1] = dlt * su[ddl][tok];
    }
    __syncthreads();
    #pragma unroll 8
    for (int tt = 0; tt < TCH; ++tt) {
      float2 dp = *(const float2*)&sdp[dl][tt][0];
      float dA = __expf(dp.x * A);
      h = fmaf(dA, h, dp.y * sB[tt][n]);
    }
  }
  // epilogue: C reduce at last token, y output
  const int btL = b * LSEQ + LSEQ - 1;
  size_t cbase = (size_t)btL * NPROJ + DTRANK + NSTATE + n;
  float Cv = part[cbase] + part[cbase + KPSTRIDE] + part[cbase + 2 * KPSTRIDE] + part[cbase + 3 * KPSTRIDE];
  float v = h * Cv;
  v += __shfl_xor(v, 1);
  v += __shfl_xor(v, 2);
  v += __shfl_xor(v, 4);
  v += __shfl_xor(v, 8);
  if (n == 0) {
    float y = v + uT[(size_t)d * BL + btL] * Dp[d];
    ybuf[b * DINNER + d] = y;   // raw y; silu(z) gate in k_head
  }
}

// ================= kernel 4: z(last) + gate + out_proj + head =================
__global__ __launch_bounds__(256) void k_head(const float* __restrict__ X,
                                              const float* __restrict__ ipw,
                                              const float* __restrict__ ybuf,
                                              const float* __restrict__ opw,
                                              const float* __restrict__ hw,
                                              const float* __restrict__ hb,
                                              float* __restrict__ out) {
  __shared__ float sx[DMODEL];
  __shared__ float sy[DINNER];
  __shared__ float ov[DMODEL];
  const int b = blockIdx.x, tid = threadIdx.x;
  sx[tid] = X[((size_t)b * LSEQ + LSEQ - 1) * DMODEL + tid];
  __syncthreads();
  #pragma unroll
  for (int rr = 0; rr < 2; ++rr) {
    int j = tid + rr * 256;
    const float* wr = &ipw[(size_t)(DINNER + j) * DMODEL];
    float z = 0.f;
    #pragma unroll 4
    for (int k = 0; k < DMODEL; k += 4) {
      float4 w4 = *(const float4*)&wr[k];
      float4 x4 = *(const float4*)&sx[k];
      z = fmaf(w4.x, x4.x, z); z = fmaf(w4.y, x4.y, z);
      z = fmaf(w4.z, x4.z, z); z = fmaf(w4.w, x4.w, z);
    }
    float yv = ybuf[b * DINNER + j];
    sy[j] = yv * z / (1.f + __expf(-z));
  }
  __syncthreads();
  {
    float s = 0.f;
    const float* wr = &opw[(size_t)tid * DINNER];
    #pragma unroll 4
    for (int k = 0; k < DINNER; k += 4) {
      float4 w4 = *(const float4*)&wr[k];
      float4 y4 = *(const float4*)&sy[k];
      s = fmaf(w4.x, y4.x, s); s = fmaf(w4.y, y4.y, s);
      s = fmaf(w4.z, y4.z, s); s = fmaf(w4.w, y4.w, s);
    }
    ov[tid] = s;
  }
  __syncthreads();
  if (tid < HORIZ) {
    float a = hb[tid];
    const float* hr = &hw[(size_t)tid * DMODEL];
    #pragma unroll 4
    for (int k = 0; k < DMODEL; k += 4) {
      float4 w4 = *(const float4*)&hr[k];
      float4 o4 = *(const float4*)&ov[k];
      a = fmaf(w4.x, o4.x, a); a = fmaf(w4.y, o4.y, a);
      a = fmaf(w4.z, o4.z, a); a = fmaf(w4.w, o4.w, a);
    }
    out[b * HORIZ + tid] = a;
  }
}

extern "C" void kernel_launch(void* const* d_in, const int* in_sizes, int n_in,
                              void* d_out, int out_size, void* d_ws, size_t ws_size,
                              hipStream_t stream) {
  (void)in_sizes; (void)n_in; (void)out_size; (void)ws_size;
  const float* x    = (const float*)d_in[0];
  const float* ipw  = (const float*)d_in[1];
  const float* cw   = (const float*)d_in[2];
  const float* cb   = (const float*)d_in[3];
  const float* xpw  = (const float*)d_in[4];
  const float* dtw  = (const float*)d_in[5];
  const float* dtb  = (const float*)d_in[6];
  const float* Alog = (const float*)d_in[7];
  const float* Dp   = (const float*)d_in[8];
  const float* opw  = (const float*)d_in[9];
  const float* hw   = (const float*)d_in[10];
  const float* hb   = (const float*)d_in[11];
  float* out = (float*)d_out;
  float* ws  = (float*)d_ws;

  float* xinT  = ws;                    // 4,194,304
  float* uT    = ws + 4194304;          // 4,194,304
  float* part  = ws + 8388608;          // 1,572,864
  float* ybuf  = ws + 9961472;          //     2,048

  k_inproj<<<dim3(64, 4), 256, 0, stream>>>(x, ipw, xinT);
  k_convdbl<<<dim3(128, 4), 256, 0, stream>>>(xinT, cw, cb, xpw, uT, part);
  k_scan<<<dim3(32, BATCH), 256, 0, stream>>>(uT, part, dtw, dtb, Alog, Dp, ybuf);
  k_head<<<BATCH, 256, 0, stream>>>(x, ipw, ybuf, opw, hw, hb, out);
}

// Round 5
// 136.881 us; speedup vs baseline: 3.4218x; 1.3941x over previous
//
#include <hip/hip_runtime.h>
#include <math.h>

#define BATCH 4
#define LSEQ 2048
#define BL (BATCH*LSEQ)        // 8192
#define DMODEL 256
#define DINNER 512
#define NSTATE 16
#define DTRANK 16
#define NPROJ 48               // DTRANK + 2*NSTATE
#define HORIZ 96
#define NCH 32                 // scan chunks
#define TCH (LSEQ/NCH)         // 64

// ================= kernel 1: x_in^T = W1 @ X^T (fp32, 128x128 tile, 8x8/thread) =================
__global__ __launch_bounds__(256) void k_inproj(const float* __restrict__ X,
                                                const float* __restrict__ W,
                                                float* __restrict__ xinT) {
  __shared__ float As[16][132];  // [k][j]
  __shared__ float Bs[16][132];  // [k][m]
  const int m0 = blockIdx.x * 128;
  const int j0 = blockIdx.y * 128;
  const int tid = threadIdx.x;
  const int lrow = tid >> 1;          // 0..127
  const int lk0  = (tid & 1) << 3;    // 0 or 8
  const int tj4  = (tid >> 4) << 2;   // 0..60
  const int tm4  = (tid & 15) << 2;   // 0..60
  const float* Arow = &W[(size_t)(j0 + lrow) * DMODEL + lk0];
  const float* Brow = &X[(size_t)(m0 + lrow) * DMODEL + lk0];
  float4 a0 = *(const float4*)(Arow);
  float4 a1 = *(const float4*)(Arow + 4);
  float4 b0 = *(const float4*)(Brow);
  float4 b1 = *(const float4*)(Brow + 4);
  float acc[8][8] = {};
  for (int k0 = 0; k0 < DMODEL; k0 += 16) {
    __syncthreads();
    As[lk0+0][lrow]=a0.x; As[lk0+1][lrow]=a0.y; As[lk0+2][lrow]=a0.z; As[lk0+3][lrow]=a0.w;
    As[lk0+4][lrow]=a1.x; As[lk0+5][lrow]=a1.y; As[lk0+6][lrow]=a1.z; As[lk0+7][lrow]=a1.w;
    Bs[lk0+0][lrow]=b0.x; Bs[lk0+1][lrow]=b0.y; Bs[lk0+2][lrow]=b0.z; Bs[lk0+3][lrow]=b0.w;
    Bs[lk0+4][lrow]=b1.x; Bs[lk0+5][lrow]=b1.y; Bs[lk0+6][lrow]=b1.z; Bs[lk0+7][lrow]=b1.w;
    __syncthreads();
    if (k0 + 16 < DMODEL) {
      a0 = *(const float4*)(Arow + k0 + 16);
      a1 = *(const float4*)(Arow + k0 + 20);
      b0 = *(const float4*)(Brow + k0 + 16);
      b1 = *(const float4*)(Brow + k0 + 20);
    }
    #pragma unroll
    for (int k = 0; k < 16; ++k) {
      float4 alo = *(const float4*)&As[k][tj4];
      float4 ahi = *(const float4*)&As[k][64 + tj4];
      float4 blo = *(const float4*)&Bs[k][tm4];
      float4 bhi = *(const float4*)&Bs[k][64 + tm4];
      float aj[8] = {alo.x,alo.y,alo.z,alo.w, ahi.x,ahi.y,ahi.z,ahi.w};
      float bm[8] = {blo.x,blo.y,blo.z,blo.w, bhi.x,bhi.y,bhi.z,bhi.w};
      #pragma unroll
      for (int i = 0; i < 8; ++i)
        #pragma unroll
        for (int j = 0; j < 8; ++j) acc[i][j] = fmaf(aj[i], bm[j], acc[i][j]);
    }
  }
  #pragma unroll
  for (int ii = 0; ii < 2; ++ii)
    #pragma unroll
    for (int i = 0; i < 4; ++i) {
      int j = j0 + ii * 64 + tj4 + i;
      int r = ii * 4 + i;
      float4 v0 = make_float4(acc[r][0], acc[r][1], acc[r][2], acc[r][3]);
      float4 v1 = make_float4(acc[r][4], acc[r][5], acc[r][6], acc[r][7]);
      *(float4*)&xinT[(size_t)j * BL + m0 + tm4] = v0;
      *(float4*)&xinT[(size_t)j * BL + m0 + 64 + tm4] = v1;
    }
}

// ================= kernel 2: conv+silu + uT + x_dbl (full K, writes dbl directly) =================
// grid 256 blocks x 32 tokens; kp loop inside (no partials).
__global__ __launch_bounds__(256) void k_convdbl(const float* __restrict__ xinT,
                                                 const float* __restrict__ cw,
                                                 const float* __restrict__ cb,
                                                 const float* __restrict__ xpw,
                                                 float* __restrict__ uT,
                                                 float* __restrict__ dbl) {
  __shared__ float sw2[48][132];   // [o][k_local]
  __shared__ float su[32][36];     // [k_sub][tok]
  const int btc = blockIdx.x;      // 0..255
  const int tid = threadIdx.x;
  const int bt0 = btc * 32;
  const bool edge0 = ((bt0 & (LSEQ - 1)) == 0);
  const int t0 = (tid & 15) << 1;  // 2 tokens
  const int o0 = (tid >> 4) * 3;   // 3 outs
  const int cr  = tid >> 3;        // conv: d within 32-sub-chunk
  const int cc4 = (tid & 7) << 2;  // conv: 4 tokens
  float acc[2][3] = {};
  for (int kp = 0; kp < 4; ++kp) {
    const int kbase = kp * 128;
    __syncthreads();               // prev xdbl done reading sw2
    for (int i = tid; i < 48 * 32; i += 256) {
      int o = i >> 5, k4 = (i & 31) << 2;
      *(float4*)&sw2[o][k4] = *(const float4*)&xpw[(size_t)o * DINNER + kbase + k4];
    }
    for (int ks = 0; ks < 4; ++ks) {
      const int dloc = ks * 32 + cr;
      const int d = kbase + dloc;
      __syncthreads();             // su free; sw2 staged (ks==0)
      {
        const float* xr = &xinT[(size_t)d * BL + bt0 + cc4];
        float4 v = *(const float4*)xr;
        bool edge = edge0 && (cc4 == 0);
        float p1, p2, p3;
        if (edge) { p1 = p2 = p3 = 0.f; }
        else { float4 lo = *(const float4*)(xr - 4); p1 = lo.y; p2 = lo.z; p3 = lo.w; }
        float4 wv = *(const float4*)&cw[d * 4];
        float bias = cb[d];
        float xv[7] = {p1, p2, p3, v.x, v.y, v.z, v.w};
        float uu[4];
        #pragma unroll
        for (int c = 0; c < 4; ++c) {
          float s = bias;
          s = fmaf(wv.x, xv[c],     s);
          s = fmaf(wv.y, xv[c + 1], s);
          s = fmaf(wv.z, xv[c + 2], s);
          s = fmaf(wv.w, xv[c + 3], s);
          uu[c] = s / (1.f + __expf(-s));
        }
        *(float4*)&su[cr][cc4] = make_float4(uu[0], uu[1], uu[2], uu[3]);
        *(float4*)&uT[(size_t)d * BL + bt0 + cc4] = make_float4(uu[0], uu[1], uu[2], uu[3]);
      }
      __syncthreads();
      #pragma unroll 8
      for (int kk = 0; kk < 32; ++kk) {
        float2 uv = *(const float2*)&su[kk][t0];
        const int kcol = ks * 32 + kk;
        float w0 = sw2[o0][kcol], w1 = sw2[o0 + 1][kcol], w2 = sw2[o0 + 2][kcol];
        acc[0][0] = fmaf(uv.x, w0, acc[0][0]);
        acc[0][1] = fmaf(uv.x, w1, acc[0][1]);
        acc[0][2] = fmaf(uv.x, w2, acc[0][2]);
        acc[1][0] = fmaf(uv.y, w0, acc[1][0]);
        acc[1][1] = fmaf(uv.y, w1, acc[1][1]);
        acc[1][2] = fmaf(uv.y, w2, acc[1][2]);
      }
    }
  }
  #pragma unroll
  for (int i = 0; i < 2; ++i)
    #pragma unroll
    for (int j = 0; j < 3; ++j)
      dbl[(size_t)(bt0 + t0 + i) * NPROJ + o0 + j] = acc[i][j];
}

// ================= kernel 3: chunked scan (delta prologue in-block), 4096 blocks =================
__global__ __launch_bounds__(256) void k_scan(const float* __restrict__ uT,
                                              const float* __restrict__ dbl,
                                              const float* __restrict__ dtw,
                                              const float* __restrict__ dtb,
                                              const float* __restrict__ Alog,
                                              float* __restrict__ aprod,
                                              float* __restrict__ hacc) {
  __shared__ float sdt[64][17];      // [tok][r] (padded: conflict-free GEMV reads)
  __shared__ float sB[64][16];       // [tok][n]
  __shared__ float sdp[16][66][2];   // [dl][tok][{delta, delta*u}] (padded)
  __shared__ float su[16][68];       // [dl][tok]
  __shared__ float sdtw[16][17];
  __shared__ float sdtb[16];
  const int dblk = blockIdx.x, c = blockIdx.y, b = blockIdx.z;
  const int tid = threadIdx.x;
  const int d0 = dblk * 16;
  const int bt0 = b * LSEQ + c * TCH;
  {
    int tok = tid >> 2, q = (tid & 3) << 2;
    float4 v = *(const float4*)&dbl[(size_t)(bt0 + tok) * NPROJ + q];
    sdt[tok][q] = v.x; sdt[tok][q + 1] = v.y; sdt[tok][q + 2] = v.z; sdt[tok][q + 3] = v.w;
    float4 w = *(const float4*)&dbl[(size_t)(bt0 + tok) * NPROJ + DTRANK + q];
    *(float4*)&sB[tok][q] = w;
    int dl = tid >> 4, tq = (tid & 15) << 2;
    *(float4*)&su[dl][tq] = *(const float4*)&uT[(size_t)(d0 + dl) * BL + bt0 + tq];
    sdtw[tid >> 4][tid & 15] = dtw[(d0 + (tid >> 4)) * DTRANK + (tid & 15)];
    if (tid < 16) sdtb[tid] = dtb[d0 + tid];
  }
  __syncthreads();
  {
    int tok = tid >> 2, dl4 = (tid & 3) << 2;
    #pragma unroll
    for (int dd = 0; dd < 4; ++dd) {
      int dl = dl4 + dd;
      float a = sdtb[dl];
      #pragma unroll
      for (int r = 0; r < DTRANK; ++r) a = fmaf(sdt[tok][r], sdtw[dl][r], a);
      float dlt = (a > 20.f) ? a : log1pf(__expf(a));
      sdp[dl][tok][0] = dlt;
      sdp[dl][tok][1] = dlt * su[dl][tok];
    }
  }
  __syncthreads();
  const int dl = tid >> 4, n = tid & 15;
  const int d = d0 + dl;
  const float A = -__expf(Alog[d * NSTATE + n]);
  float ap = 1.f, h = 0.f;
  #pragma unroll 8
  for (int tt = 0; tt < TCH; ++tt) {
    float2 dp = *(const float2*)&sdp[dl][tt][0];
    float dA = __expf(dp.x * A);
    h = fmaf(dA, h, dp.y * sB[tt][n]);
    ap *= dA;
  }
  size_t off = (((size_t)b * NCH + c) * DINNER + d) * NSTATE + n;
  aprod[off] = ap;
  hacc[off] = h;
}

// ================= kernel 4: combine chunks -> y (raw) =================
__global__ __launch_bounds__(256) void k_combine(const float* __restrict__ aprod,
                                                 const float* __restrict__ hacc,
                                                 const float* __restrict__ dbl,
                                                 const float* __restrict__ uT,
                                                 const float* __restrict__ Dp,
                                                 float* __restrict__ ybuf) {
  const int dblk = blockIdx.x & 31, b = blockIdx.x >> 5;
  const int tid = threadIdx.x;
  const int dl = tid >> 4, n = tid & 15;
  const int d = dblk * 16 + dl;
  float h = 0.f;
  for (int c = 0; c < NCH; ++c) {
    size_t off = (((size_t)b * NCH + c) * DINNER + d) * NSTATE + n;
    h = fmaf(aprod[off], h, hacc[off]);
  }
  const int btL = b * LSEQ + LSEQ - 1;
  float Cv = dbl[(size_t)btL * NPROJ + DTRANK + NSTATE + n];
  float v = h * Cv;
  v += __shfl_xor(v, 1);
  v += __shfl_xor(v, 2);
  v += __shfl_xor(v, 4);
  v += __shfl_xor(v, 8);
  if (n == 0) {
    float y = v + uT[(size_t)d * BL + btL] * Dp[d];
    ybuf[b * DINNER + d] = y;   // raw y; silu(z) gate in k_head
  }
}

// ================= kernel 5: z(last) + gate + out_proj + head =================
__global__ __launch_bounds__(256) void k_head(const float* __restrict__ X,
                                              const float* __restrict__ ipw,
                                              const float* __restrict__ ybuf,
                                              const float* __restrict__ opw,
                                              const float* __restrict__ hw,
                                              const float* __restrict__ hb,
                                              float* __restrict__ out) {
  __shared__ float sx[DMODEL];
  __shared__ float sy[DINNER];
  __shared__ float ov[DMODEL];
  const int b = blockIdx.x, tid = threadIdx.x;
  sx[tid] = X[((size_t)b * LSEQ + LSEQ - 1) * DMODEL + tid];
  __syncthreads();
  #pragma unroll
  for (int rr = 0; rr < 2; ++rr) {
    int j = tid + rr * 256;
    const float* wr = &ipw[(size_t)(DINNER + j) * DMODEL];
    float z = 0.f;
    #pragma unroll 4
    for (int k = 0; k < DMODEL; k += 4) {
      float4 w4 = *(const float4*)&wr[k];
      float4 x4 = *(const float4*)&sx[k];
      z = fmaf(w4.x, x4.x, z); z = fmaf(w4.y, x4.y, z);
      z = fmaf(w4.z, x4.z, z); z = fmaf(w4.w, x4.w, z);
    }
    float yv = ybuf[b * DINNER + j];
    sy[j] = yv * z / (1.f + __expf(-z));
  }
  __syncthreads();
  {
    float s = 0.f;
    const float* wr = &opw[(size_t)tid * DINNER];
    #pragma unroll 4
    for (int k = 0; k < DINNER; k += 4) {
      float4 w4 = *(const float4*)&wr[k];
      float4 y4 = *(const float4*)&sy[k];
      s = fmaf(w4.x, y4.x, s); s = fmaf(w4.y, y4.y, s);
      s = fmaf(w4.z, y4.z, s); s = fmaf(w4.w, y4.w, s);
    }
    ov[tid] = s;
  }
  __syncthreads();
  if (tid < HORIZ) {
    float a = hb[tid];
    const float* hr = &hw[(size_t)tid * DMODEL];
    #pragma unroll 4
    for (int k = 0; k < DMODEL; k += 4) {
      float4 w4 = *(const float4*)&hr[k];
      float4 o4 = *(const float4*)&ov[k];
      a = fmaf(w4.x, o4.x, a); a = fmaf(w4.y, o4.y, a);
      a = fmaf(w4.z, o4.z, a); a = fmaf(w4.w, o4.w, a);
    }
    out[b * HORIZ + tid] = a;
  }
}

extern "C" void kernel_launch(void* const* d_in, const int* in_sizes, int n_in,
                              void* d_out, int out_size, void* d_ws, size_t ws_size,
                              hipStream_t stream) {
  (void)in_sizes; (void)n_in; (void)out_size; (void)ws_size;
  const float* x    = (const float*)d_in[0];
  const float* ipw  = (const float*)d_in[1];
  const float* cw   = (const float*)d_in[2];
  const float* cb   = (const float*)d_in[3];
  const float* xpw  = (const float*)d_in[4];
  const float* dtw  = (const float*)d_in[5];
  const float* dtb  = (const float*)d_in[6];
  const float* Alog = (const float*)d_in[7];
  const float* Dp   = (const float*)d_in[8];
  const float* opw  = (const float*)d_in[9];
  const float* hw   = (const float*)d_in[10];
  const float* hb   = (const float*)d_in[11];
  float* out = (float*)d_out;
  float* ws  = (float*)d_ws;

  float* xinT  = ws;                    // 4,194,304
  float* uT    = ws + 4194304;          // 4,194,304
  float* dbl   = ws + 8388608;          //   393,216
  float* aprod = ws + 8781824;          // 1,048,576
  float* hacc  = ws + 9830400;          // 1,048,576
  float* ybuf  = ws + 10878976;         //     2,048

  k_inproj<<<dim3(64, 4), 256, 0, stream>>>(x, ipw, xinT);
  k_convdbl<<<256, 256, 0, stream>>>(xinT, cw, cb, xpw, uT, dbl);
  k_scan<<<dim3(32, NCH, BATCH), 256, 0, stream>>>(uT, dbl, dtw, dtb, Alog, aprod, hacc);
  k_combine<<<128, 256, 0, stream>>>(aprod, hacc, dbl, uT, Dp, ybuf);
  k_head<<<BATCH, 256, 0, stream>>>(x, ipw, ybuf, opw, hw, hb, out);
}

// Round 6
// 103.247 us; speedup vs baseline: 4.5365x; 1.3258x over previous
//
#include <hip/hip_runtime.h>
#include <math.h>

#define BATCH 4
#define LSEQ 2048
#define BL (BATCH*LSEQ)        // 8192
#define DMODEL 256
#define DINNER 512
#define NSTATE 16
#define DTRANK 16
#define NPROJ 48               // DTRANK + 2*NSTATE
#define HORIZ 96
#define NCH 32                 // scan chunks
#define TCH (LSEQ/NCH)         // 64

// ================= kernel 1: x_in^T = W1 @ X^T (fp32, 128x128 tile, 8x8/thread) =================
__global__ __launch_bounds__(256) void k_inproj(const float* __restrict__ X,
                                                const float* __restrict__ W,
                                                float* __restrict__ xinT) {
  __shared__ float As[16][132];  // [k][j]
  __shared__ float Bs[16][132];  // [k][m]
  const int m0 = blockIdx.x * 128;
  const int j0 = blockIdx.y * 128;
  const int tid = threadIdx.x;
  const int lrow = tid >> 1;          // 0..127
  const int lk0  = (tid & 1) << 3;    // 0 or 8
  const int tj4  = (tid >> 4) << 2;   // 0..60
  const int tm4  = (tid & 15) << 2;   // 0..60
  const float* Arow = &W[(size_t)(j0 + lrow) * DMODEL + lk0];
  const float* Brow = &X[(size_t)(m0 + lrow) * DMODEL + lk0];
  float4 a0 = *(const float4*)(Arow);
  float4 a1 = *(const float4*)(Arow + 4);
  float4 b0 = *(const float4*)(Brow);
  float4 b1 = *(const float4*)(Brow + 4);
  float acc[8][8] = {};
  for (int k0 = 0; k0 < DMODEL; k0 += 16) {
    __syncthreads();
    As[lk0+0][lrow]=a0.x; As[lk0+1][lrow]=a0.y; As[lk0+2][lrow]=a0.z; As[lk0+3][lrow]=a0.w;
    As[lk0+4][lrow]=a1.x; As[lk0+5][lrow]=a1.y; As[lk0+6][lrow]=a1.z; As[lk0+7][lrow]=a1.w;
    Bs[lk0+0][lrow]=b0.x; Bs[lk0+1][lrow]=b0.y; Bs[lk0+2][lrow]=b0.z; Bs[lk0+3][lrow]=b0.w;
    Bs[lk0+4][lrow]=b1.x; Bs[lk0+5][lrow]=b1.y; Bs[lk0+6][lrow]=b1.z; Bs[lk0+7][lrow]=b1.w;
    __syncthreads();
    if (k0 + 16 < DMODEL) {
      a0 = *(const float4*)(Arow + k0 + 16);
      a1 = *(const float4*)(Arow + k0 + 20);
      b0 = *(const float4*)(Brow + k0 + 16);
      b1 = *(const float4*)(Brow + k0 + 20);
    }
    #pragma unroll
    for (int k = 0; k < 16; ++k) {
      float4 alo = *(const float4*)&As[k][tj4];
      float4 ahi = *(const float4*)&As[k][64 + tj4];
      float4 blo = *(const float4*)&Bs[k][tm4];
      float4 bhi = *(const float4*)&Bs[k][64 + tm4];
      float aj[8] = {alo.x,alo.y,alo.z,alo.w, ahi.x,ahi.y,ahi.z,ahi.w};
      float bm[8] = {blo.x,blo.y,blo.z,blo.w, bhi.x,bhi.y,bhi.z,bhi.w};
      #pragma unroll
      for (int i = 0; i < 8; ++i)
        #pragma unroll
        for (int j = 0; j < 8; ++j) acc[i][j] = fmaf(aj[i], bm[j], acc[i][j]);
    }
  }
  #pragma unroll
  for (int ii = 0; ii < 2; ++ii)
    #pragma unroll
    for (int i = 0; i < 4; ++i) {
      int j = j0 + ii * 64 + tj4 + i;
      int r = ii * 4 + i;
      float4 v0 = make_float4(acc[r][0], acc[r][1], acc[r][2], acc[r][3]);
      float4 v1 = make_float4(acc[r][4], acc[r][5], acc[r][6], acc[r][7]);
      *(float4*)&xinT[(size_t)j * BL + m0 + tm4] = v0;
      *(float4*)&xinT[(size_t)j * BL + m0 + 64 + tm4] = v1;
    }
}

// ================= kernel 2: conv+silu + uT + x_dbl (full K) ; blocks>=256: hwf = hw @ opw =================
__global__ __launch_bounds__(256) void k_convdbl(const float* __restrict__ xinT,
                                                 const float* __restrict__ cw,
                                                 const float* __restrict__ cb,
                                                 const float* __restrict__ xpw,
                                                 const float* __restrict__ opw,
                                                 const float* __restrict__ hw,
                                                 float* __restrict__ uT,
                                                 float* __restrict__ dbl,
                                                 float* __restrict__ hwf) {
  __shared__ float sw2[48][132];   // [o][k_local]  (fusew path reuses as scratch)
  __shared__ float su[32][36];     // [k_sub][tok]
  const int btc = blockIdx.x;
  const int tid = threadIdx.x;
  if (btc >= 256) {                // ---- fused-weight blocks: hwf[t][k] = sum_m hw[t][m]*opw[m][k]
    const int fid = btc - 256;     // 0..63
    const int k0 = fid * 8;
    const int kk = tid & 7;
    const int t0 = tid >> 3;       // 0..31
    float* scratch = &sw2[0][0];   // stage opw[:, k0..k0+8] -> [m][8]
    for (int i = tid; i < 512; i += 256) {
      int m = i >> 1, half = (i & 1) << 2;
      *(float4*)&scratch[m * 8 + half] = *(const float4*)&opw[(size_t)m * DINNER + k0 + half];
    }
    __syncthreads();
    #pragma unroll
    for (int tb = 0; tb < 3; ++tb) {
      int t = tb * 32 + t0;
      const float* hr = &hw[(size_t)t * DMODEL];
      float acc = 0.f;
      #pragma unroll 8
      for (int m = 0; m < DMODEL; ++m) acc = fmaf(hr[m], scratch[m * 8 + kk], acc);
      hwf[(size_t)t * DINNER + k0 + kk] = acc;
    }
    return;
  }
  const int bt0 = btc * 32;
  const bool edge0 = ((bt0 & (LSEQ - 1)) == 0);
  const int t0 = (tid & 15) << 1;  // 2 tokens
  const int o0 = (tid >> 4) * 3;   // 3 outs
  const int cr  = tid >> 3;        // conv: d within 32-sub-chunk
  const int cc4 = (tid & 7) << 2;  // conv: 4 tokens
  float acc[2][3] = {};
  for (int kp = 0; kp < 4; ++kp) {
    const int kbase = kp * 128;
    __syncthreads();               // prev xdbl done reading sw2
    for (int i = tid; i < 48 * 32; i += 256) {
      int o = i >> 5, k4 = (i & 31) << 2;
      *(float4*)&sw2[o][k4] = *(const float4*)&xpw[(size_t)o * DINNER + kbase + k4];
    }
    for (int ks = 0; ks < 4; ++ks) {
      const int dloc = ks * 32 + cr;
      const int d = kbase + dloc;
      __syncthreads();             // su free; sw2 staged (ks==0)
      {
        const float* xr = &xinT[(size_t)d * BL + bt0 + cc4];
        float4 v = *(const float4*)xr;
        bool edge = edge0 && (cc4 == 0);
        float p1, p2, p3;
        if (edge) { p1 = p2 = p3 = 0.f; }
        else { float4 lo = *(const float4*)(xr - 4); p1 = lo.y; p2 = lo.z; p3 = lo.w; }
        float4 wv = *(const float4*)&cw[d * 4];
        float bias = cb[d];
        float xv[7] = {p1, p2, p3, v.x, v.y, v.z, v.w};
        float uu[4];
        #pragma unroll
        for (int c = 0; c < 4; ++c) {
          float s = bias;
          s = fmaf(wv.x, xv[c],     s);
          s = fmaf(wv.y, xv[c + 1], s);
          s = fmaf(wv.z, xv[c + 2], s);
          s = fmaf(wv.w, xv[c + 3], s);
          uu[c] = s / (1.f + __expf(-s));
        }
        *(float4*)&su[cr][cc4] = make_float4(uu[0], uu[1], uu[2], uu[3]);
        *(float4*)&uT[(size_t)d * BL + bt0 + cc4] = make_float4(uu[0], uu[1], uu[2], uu[3]);
      }
      __syncthreads();
      #pragma unroll 8
      for (int kk = 0; kk < 32; ++kk) {
        float2 uv = *(const float2*)&su[kk][t0];
        const int kcol = ks * 32 + kk;
        float w0 = sw2[o0][kcol], w1 = sw2[o0 + 1][kcol], w2 = sw2[o0 + 2][kcol];
        acc[0][0] = fmaf(uv.x, w0, acc[0][0]);
        acc[0][1] = fmaf(uv.x, w1, acc[0][1]);
        acc[0][2] = fmaf(uv.x, w2, acc[0][2]);
        acc[1][0] = fmaf(uv.y, w0, acc[1][0]);
        acc[1][1] = fmaf(uv.y, w1, acc[1][1]);
        acc[1][2] = fmaf(uv.y, w2, acc[1][2]);
      }
    }
  }
  #pragma unroll
  for (int i = 0; i < 2; ++i)
    #pragma unroll
    for (int j = 0; j < 3; ++j)
      dbl[(size_t)(bt0 + t0 + i) * NPROJ + o0 + j] = acc[i][j];
}

// ================= kernel 3: chunked scan (delta prologue in-block), 4096 blocks =================
__global__ __launch_bounds__(256) void k_scan(const float* __restrict__ uT,
                                              const float* __restrict__ dbl,
                                              const float* __restrict__ dtw,
                                              const float* __restrict__ dtb,
                                              const float* __restrict__ Alog,
                                              float* __restrict__ aprod,
                                              float* __restrict__ hacc) {
  __shared__ float sdt[64][17];      // [tok][r] (padded)
  __shared__ float sB[64][16];       // [tok][n]
  __shared__ float sdp[16][66][2];   // [dl][tok][{delta, delta*u}] (padded)
  __shared__ float su[16][68];       // [dl][tok]
  __shared__ float sdtw[16][17];
  __shared__ float sdtb[16];
  const int dblk = blockIdx.x, c = blockIdx.y, b = blockIdx.z;
  const int tid = threadIdx.x;
  const int d0 = dblk * 16;
  const int bt0 = b * LSEQ + c * TCH;
  {
    int tok = tid >> 2, q = (tid & 3) << 2;
    float4 v = *(const float4*)&dbl[(size_t)(bt0 + tok) * NPROJ + q];
    sdt[tok][q] = v.x; sdt[tok][q + 1] = v.y; sdt[tok][q + 2] = v.z; sdt[tok][q + 3] = v.w;
    float4 w = *(const float4*)&dbl[(size_t)(bt0 + tok) * NPROJ + DTRANK + q];
    *(float4*)&sB[tok][q] = w;
    int dl = tid >> 4, tq = (tid & 15) << 2;
    *(float4*)&su[dl][tq] = *(const float4*)&uT[(size_t)(d0 + dl) * BL + bt0 + tq];
    sdtw[tid >> 4][tid & 15] = dtw[(d0 + (tid >> 4)) * DTRANK + (tid & 15)];
    if (tid < 16) sdtb[tid] = dtb[d0 + tid];
  }
  __syncthreads();
  {
    int tok = tid >> 2, dl4 = (tid & 3) << 2;
    #pragma unroll
    for (int dd = 0; dd < 4; ++dd) {
      int dl = dl4 + dd;
      float a = sdtb[dl];
      #pragma unroll
      for (int r = 0; r < DTRANK; ++r) a = fmaf(sdt[tok][r], sdtw[dl][r], a);
      float dlt = (a > 20.f) ? a : log1pf(__expf(a));
      sdp[dl][tok][0] = dlt;
      sdp[dl][tok][1] = dlt * su[dl][tok];
    }
  }
  __syncthreads();
  const int dl = tid >> 4, n = tid & 15;
  const int d = d0 + dl;
  const float A = -__expf(Alog[d * NSTATE + n]);
  float ap = 1.f, h = 0.f;
  #pragma unroll 8
  for (int tt = 0; tt < TCH; ++tt) {
    float2 dp = *(const float2*)&sdp[dl][tt][0];
    float dA = __expf(dp.x * A);
    h = fmaf(dA, h, dp.y * sB[tt][n]);
    ap *= dA;
  }
  size_t off = (((size_t)b * NCH + c) * DINNER + d) * NSTATE + n;
  aprod[off] = ap;
  hacc[off] = h;
}

// ================= kernel 4: combine chunks + z-gate -> sy =================
__global__ __launch_bounds__(256) void k_combine(const float* __restrict__ aprod,
                                                 const float* __restrict__ hacc,
                                                 const float* __restrict__ dbl,
                                                 const float* __restrict__ uT,
                                                 const float* __restrict__ Dp,
                                                 const float* __restrict__ X,
                                                 const float* __restrict__ ipw,
                                                 float* __restrict__ ybuf) {
  __shared__ float sx[DMODEL];
  const int dblk = blockIdx.x & 31, b = blockIdx.x >> 5;
  const int tid = threadIdx.x;
  const int dl = tid >> 4, n = tid & 15;
  const int d = dblk * 16 + dl;
  sx[tid] = X[((size_t)b * LSEQ + LSEQ - 1) * DMODEL + tid];
  float h = 0.f;
  for (int c = 0; c < NCH; ++c) {
    size_t off = (((size_t)b * NCH + c) * DINNER + d) * NSTATE + n;
    h = fmaf(aprod[off], h, hacc[off]);
  }
  __syncthreads();
  // z partial: lanes n cover k = n*16..n*16+15 of the z-row DINNER+d
  float zp = 0.f;
  {
    const float* zr = &ipw[(size_t)(DINNER + d) * DMODEL + (n << 4)];
    #pragma unroll
    for (int q = 0; q < 4; ++q) {
      float4 w4 = *(const float4*)&zr[q << 2];
      float4 x4 = *(const float4*)&sx[(n << 4) + (q << 2)];
      zp = fmaf(w4.x, x4.x, zp); zp = fmaf(w4.y, x4.y, zp);
      zp = fmaf(w4.z, x4.z, zp); zp = fmaf(w4.w, x4.w, zp);
    }
  }
  const int btL = b * LSEQ + LSEQ - 1;
  float Cv = dbl[(size_t)btL * NPROJ + DTRANK + NSTATE + n];
  float v = h * Cv;
  #pragma unroll
  for (int off = 1; off < 16; off <<= 1) {
    v  += __shfl_xor(v, off);
    zp += __shfl_xor(zp, off);
  }
  if (n == 0) {
    float y = v + uT[(size_t)d * BL + btL] * Dp[d];
    ybuf[b * DINNER + d] = y * zp / (1.f + __expf(-zp));   // gated sy
  }
}

// ================= kernel 5: out = sy @ hwf^T + hb  (one wave per (b,t)) =================
__global__ __launch_bounds__(256) void k_out(const float* __restrict__ sy,
                                             const float* __restrict__ hwf,
                                             const float* __restrict__ hb,
                                             float* __restrict__ out) {
  const int t = blockIdx.x;            // 0..95
  const int b = threadIdx.x >> 6;      // 0..3
  const int lane = threadIdx.x & 63;
  const int k0 = lane << 3;
  const float* yr = &sy[(size_t)b * DINNER + k0];
  const float* wr = &hwf[(size_t)t * DINNER + k0];
  float4 y0 = *(const float4*)yr, y1 = *(const float4*)(yr + 4);
  float4 w0 = *(const float4*)wr, w1 = *(const float4*)(wr + 4);
  float s = y0.x * w0.x + y0.y * w0.y + y0.z * w0.z + y0.w * w0.w
          + y1.x * w1.x + y1.y * w1.y + y1.z * w1.z + y1.w * w1.w;
  #pragma unroll
  for (int off = 1; off < 64; off <<= 1) s += __shfl_xor(s, off);
  if (lane == 0) out[b * HORIZ + t] = s + hb[t];
}

extern "C" void kernel_launch(void* const* d_in, const int* in_sizes, int n_in,
                              void* d_out, int out_size, void* d_ws, size_t ws_size,
                              hipStream_t stream) {
  (void)in_sizes; (void)n_in; (void)out_size; (void)ws_size;
  const float* x    = (const float*)d_in[0];
  const float* ipw  = (const float*)d_in[1];
  const float* cw   = (const float*)d_in[2];
  const float* cb   = (const float*)d_in[3];
  const float* xpw  = (const float*)d_in[4];
  const float* dtw  = (const float*)d_in[5];
  const float* dtb  = (const float*)d_in[6];
  const float* Alog = (const float*)d_in[7];
  const float* Dp   = (const float*)d_in[8];
  const float* opw  = (const float*)d_in[9];
  const float* hw   = (const float*)d_in[10];
  const float* hb   = (const float*)d_in[11];
  float* out = (float*)d_out;
  float* ws  = (float*)d_ws;

  float* xinT  = ws;                    // 4,194,304
  float* uT    = ws + 4194304;          // 4,194,304
  float* dbl   = ws + 8388608;          //   393,216
  float* aprod = ws + 8781824;          // 1,048,576
  float* hacc  = ws + 9830400;          // 1,048,576
  float* ybuf  = ws + 10878976;         //     2,048
  float* hwf   = ws + 10881024;         //    49,152

  k_inproj<<<dim3(64, 4), 256, 0, stream>>>(x, ipw, xinT);
  k_convdbl<<<320, 256, 0, stream>>>(xinT, cw, cb, xpw, opw, hw, uT, dbl, hwf);
  k_scan<<<dim3(32, NCH, BATCH), 256, 0, stream>>>(uT, dbl, dtw, dtb, Alog, aprod, hacc);
  k_combine<<<128, 256, 0, stream>>>(aprod, hacc, dbl, uT, Dp, x, ipw, ybuf);
  k_out<<<HORIZ, 256, 0, stream>>>(ybuf, hwf, hb, out);
}

// Round 7
// 77.018 us; speedup vs baseline: 6.0814x; 1.3406x over previous
//
#include <hip/hip_runtime.h>
#include <math.h>

#define BATCH 4
#define LSEQ 2048
#define BL (BATCH*LSEQ)        // 8192
#define DMODEL 256
#define DINNER 512
#define NSTATE 16
#define DTRANK 16
#define NPROJ 48               // DTRANK + 2*NSTATE
#define HORIZ 96
#define NCH 32                 // scan chunks
#define TCH (LSEQ/NCH)         // 64

typedef __attribute__((ext_vector_type(8))) short short8b;  // 8 bf16
typedef __attribute__((ext_vector_type(4))) float f32x4;

__device__ __forceinline__ unsigned short f2bf(float f) {
  unsigned u = __float_as_uint(f);
  u += 0x7FFF + ((u >> 16) & 1);          // round-to-nearest-even
  return (unsigned short)(u >> 16);
}

// ================= kernel 1: xinT[j][m] = sum_k W[j][k]*X[m][k] via bf16 MFMA =================
// 128x128 tile, BK=32, 4 waves x (64x64 = 4x4 frags of 16x16x32).
__global__ __launch_bounds__(256) void k_inproj(const float* __restrict__ X,
                                                const float* __restrict__ W,
                                                float* __restrict__ xinT) {
  __shared__ unsigned short sA[128][40];   // [j][k] bf16, 80B row stride (aligned+bank-uniform)
  __shared__ unsigned short sB[128][40];   // [m][k]
  const int m0 = blockIdx.x * 128;
  const int j0 = blockIdx.y * 128;
  const int tid = threadIdx.x;
  const int lane = tid & 63;
  const int wave = tid >> 6;
  const int jw = (wave & 1) * 64;
  const int mw = (wave >> 1) * 64;
  const int r  = tid >> 1;                 // staging row 0..127
  const int kh = (tid & 1) * 16;           // k-half 0/16
  const int fl = lane & 15;
  const int fg = lane >> 4;                // k-octet group
  const float* Asrc = &W[(size_t)(j0 + r) * DMODEL + kh];
  const float* Bsrc = &X[(size_t)(m0 + r) * DMODEL + kh];
  f32x4 acc[4][4];
  #pragma unroll
  for (int f = 0; f < 4; ++f)
    #pragma unroll
    for (int g = 0; g < 4; ++g) acc[f][g] = (f32x4){0.f, 0.f, 0.f, 0.f};
  float4 av[4], bv[4];
  #pragma unroll
  for (int q = 0; q < 4; ++q) {
    av[q] = *(const float4*)(Asrc + 4 * q);
    bv[q] = *(const float4*)(Bsrc + 4 * q);
  }
  for (int kb = 0; kb < DMODEL; kb += 32) {
    __syncthreads();                       // prior compute done with LDS
    {
      unsigned short ta[16], tb[16];
      #pragma unroll
      for (int q = 0; q < 4; ++q) {
        ta[4*q+0]=f2bf(av[q].x); ta[4*q+1]=f2bf(av[q].y); ta[4*q+2]=f2bf(av[q].z); ta[4*q+3]=f2bf(av[q].w);
        tb[4*q+0]=f2bf(bv[q].x); tb[4*q+1]=f2bf(bv[q].y); tb[4*q+2]=f2bf(bv[q].z); tb[4*q+3]=f2bf(bv[q].w);
      }
      *(short8b*)&sA[r][kh]     = *(short8b*)&ta[0];
      *(short8b*)&sA[r][kh + 8] = *(short8b*)&ta[8];
      *(short8b*)&sB[r][kh]     = *(short8b*)&tb[0];
      *(short8b*)&sB[r][kh + 8] = *(short8b*)&tb[8];
    }
    __syncthreads();                       // staging visible
    if (kb + 32 < DMODEL) {
      #pragma unroll
      for (int q = 0; q < 4; ++q) {
        av[q] = *(const float4*)(Asrc + kb + 32 + 4 * q);
        bv[q] = *(const float4*)(Bsrc + kb + 32 + 4 * q);
      }
    }
    short8b af[4], bf[4];
    #pragma unroll
    for (int f = 0; f < 4; ++f) {
      af[f] = *(const short8b*)&sA[jw + f * 16 + fl][fg * 8];
      bf[f] = *(const short8b*)&sB[mw + f * 16 + fl][fg * 8];
    }
    #pragma unroll
    for (int f = 0; f < 4; ++f)
      #pragma unroll
      for (int g = 0; g < 4; ++g)
        acc[f][g] = __builtin_amdgcn_mfma_f32_16x16x32_bf16(af[f], bf[g], acc[f][g], 0, 0, 0);
  }
  // D mapping (m89-verified): col = lane&15 (m), row = (lane>>4)*4 + reg (j)
  #pragma unroll
  for (int f = 0; f < 4; ++f) {
    const int j = j0 + jw + f * 16 + fg * 4;
    #pragma unroll
    for (int g = 0; g < 4; ++g) {
      const int m = m0 + mw + g * 16 + fl;
      #pragma unroll
      for (int rg = 0; rg < 4; ++rg)
        xinT[(size_t)(j + rg) * BL + m] = acc[f][g][rg];
    }
  }
}

// ================= kernel 2: conv+silu + uT + x_dbl (full K) ; blocks>=256: hwf = hw @ opw =================
__global__ __launch_bounds__(256) void k_convdbl(const float* __restrict__ xinT,
                                                 const float* __restrict__ cw,
                                                 const float* __restrict__ cb,
                                                 const float* __restrict__ xpw,
                                                 const float* __restrict__ opw,
                                                 const float* __restrict__ hw,
                                                 float* __restrict__ uT,
                                                 float* __restrict__ dbl,
                                                 float* __restrict__ hwf) {
  __shared__ float sw2[48][132];   // [o][k_local] (fusew path reuses as scratch)
  __shared__ float su[128][33];    // [dloc][tok]
  const int btc = blockIdx.x;
  const int tid = threadIdx.x;
  if (btc >= 256) {                // ---- fused-weight blocks: hwf[t][k] = sum_m hw[t][m]*opw[m][k]
    const int fid = btc - 256;     // 0..63
    const int k0 = fid * 8;
    const int kk = tid & 7;
    const int t0 = tid >> 3;       // 0..31
    float* scratch = &sw2[0][0];   // stage opw[:, k0..k0+8) -> [m][8]
    for (int i = tid; i < 512; i += 256) {
      int m = i >> 1, half = (i & 1) << 2;
      *(float4*)&scratch[m * 8 + half] = *(const float4*)&opw[(size_t)m * DINNER + k0 + half];
    }
    __syncthreads();
    #pragma unroll
    for (int tb = 0; tb < 3; ++tb) {
      int t = tb * 32 + t0;
      const float* hr = &hw[(size_t)t * DMODEL];
      float acc = 0.f;
      #pragma unroll 8
      for (int m = 0; m < DMODEL; ++m) acc = fmaf(hr[m], scratch[m * 8 + kk], acc);
      hwf[(size_t)t * DINNER + k0 + kk] = acc;
    }
    return;
  }
  const int bt0 = btc * 32;
  const bool edge0 = ((bt0 & (LSEQ - 1)) == 0);
  const int t0 = (tid & 15) << 1;  // 2 tokens (xdbl)
  const int o0 = (tid >> 4) * 3;   // 3 outs (xdbl)
  const int cr = tid >> 1;         // conv: channel 0..127
  const int cc = (tid & 1) << 4;   // conv: token 0/16
  float acc[2][3] = {};
  for (int kp = 0; kp < 4; ++kp) {
    const int kbase = kp * 128;
    __syncthreads();               // sw2+su free
    #pragma unroll
    for (int q = 0; q < 6; ++q) {
      int idx = tid + q * 256;     // float4 units, 1536 total
      int o = idx >> 5, k4 = (idx & 31) << 2;
      *(float4*)&sw2[o][k4] = *(const float4*)&xpw[(size_t)o * DINNER + kbase + k4];
    }
    {
      const int d = kbase + cr;
      const float* xr = &xinT[(size_t)d * BL + bt0 + cc];
      float4 v0 = *(const float4*)xr;
      float4 v1 = *(const float4*)(xr + 4);
      float4 v2 = *(const float4*)(xr + 8);
      float4 v3 = *(const float4*)(xr + 12);
      bool edge = edge0 && (cc == 0);
      float p1, p2, p3;
      if (edge) { p1 = p2 = p3 = 0.f; }
      else { p1 = xr[-3]; p2 = xr[-2]; p3 = xr[-1]; }
      float4 wv = *(const float4*)&cw[d * 4];
      float bias = cb[d];
      float xv[19] = {p1, p2, p3, v0.x, v0.y, v0.z, v0.w, v1.x, v1.y, v1.z, v1.w,
                      v2.x, v2.y, v2.z, v2.w, v3.x, v3.y, v3.z, v3.w};
      float uu[16];
      #pragma unroll
      for (int c = 0; c < 16; ++c) {
        float s = bias;
        s = fmaf(wv.x, xv[c],     s);
        s = fmaf(wv.y, xv[c + 1], s);
        s = fmaf(wv.z, xv[c + 2], s);
        s = fmaf(wv.w, xv[c + 3], s);
        uu[c] = s / (1.f + __expf(-s));
      }
      #pragma unroll
      for (int q = 0; q < 4; ++q) {
        float4 w4 = make_float4(uu[4*q], uu[4*q+1], uu[4*q+2], uu[4*q+3]);
        *(float4*)&su[cr][cc + 4*q] = w4;
        *(float4*)&uT[(size_t)d * BL + bt0 + cc + 4*q] = w4;
      }
    }
    __syncthreads();
    #pragma unroll 4
    for (int kk = 0; kk < 128; ++kk) {
      float2 uv = *(const float2*)&su[kk][t0];
      float w0 = sw2[o0][kk], w1 = sw2[o0 + 1][kk], w2 = sw2[o0 + 2][kk];
      acc[0][0] = fmaf(uv.x, w0, acc[0][0]);
      acc[0][1] = fmaf(uv.x, w1, acc[0][1]);
      acc[0][2] = fmaf(uv.x, w2, acc[0][2]);
      acc[1][0] = fmaf(uv.y, w0, acc[1][0]);
      acc[1][1] = fmaf(uv.y, w1, acc[1][1]);
      acc[1][2] = fmaf(uv.y, w2, acc[1][2]);
    }
  }
  #pragma unroll
  for (int i = 0; i < 2; ++i)
    #pragma unroll
    for (int j = 0; j < 3; ++j)
      dbl[(size_t)(bt0 + t0 + i) * NPROJ + o0 + j] = acc[i][j];
}

// ================= kernel 3: chunked scan (delta prologue in-block), 4096 blocks =================
__global__ __launch_bounds__(256) void k_scan(const float* __restrict__ uT,
                                              const float* __restrict__ dbl,
                                              const float* __restrict__ dtw,
                                              const float* __restrict__ dtb,
                                              const float* __restrict__ Alog,
                                              float* __restrict__ aprod,
                                              float* __restrict__ hacc) {
  __shared__ float sdt[64][17];      // [tok][r] (padded)
  __shared__ float sB[64][16];       // [tok][n]
  __shared__ float sdp[16][66][2];   // [dl][tok][{delta, delta*u}] (padded)
  __shared__ float su[16][68];       // [dl][tok]
  __shared__ float sdtw[16][17];
  __shared__ float sdtb[16];
  const int dblk = blockIdx.x, c = blockIdx.y, b = blockIdx.z;
  const int tid = threadIdx.x;
  const int d0 = dblk * 16;
  const int bt0 = b * LSEQ + c * TCH;
  {
    int tok = tid >> 2, q = (tid & 3) << 2;
    float4 v = *(const float4*)&dbl[(size_t)(bt0 + tok) * NPROJ + q];
    sdt[tok][q] = v.x; sdt[tok][q + 1] = v.y; sdt[tok][q + 2] = v.z; sdt[tok][q + 3] = v.w;
    float4 w = *(const float4*)&dbl[(size_t)(bt0 + tok) * NPROJ + DTRANK + q];
    *(float4*)&sB[tok][q] = w;
    int dl = tid >> 4, tq = (tid & 15) << 2;
    *(float4*)&su[dl][tq] = *(const float4*)&uT[(size_t)(d0 + dl) * BL + bt0 + tq];
    sdtw[tid >> 4][tid & 15] = dtw[(d0 + (tid >> 4)) * DTRANK + (tid & 15)];
    if (tid < 16) sdtb[tid] = dtb[d0 + tid];
  }
  __syncthreads();
  {
    int tok = tid >> 2, dl4 = (tid & 3) << 2;
    #pragma unroll
    for (int dd = 0; dd < 4; ++dd) {
      int dl = dl4 + dd;
      float a = sdtb[dl];
      #pragma unroll
      for (int r = 0; r < DTRANK; ++r) a = fmaf(sdt[tok][r], sdtw[dl][r], a);
      float dlt = (a > 20.f) ? a : log1pf(__expf(a));
      sdp[dl][tok][0] = dlt;
      sdp[dl][tok][1] = dlt * su[dl][tok];
    }
  }
  __syncthreads();
  const int dl = tid >> 4, n = tid & 15;
  const int d = d0 + dl;
  const float A = -__expf(Alog[d * NSTATE + n]);
  float ap = 1.f, h = 0.f;
  #pragma unroll 8
  for (int tt = 0; tt < TCH; ++tt) {
    float2 dp = *(const float2*)&sdp[dl][tt][0];
    float dA = __expf(dp.x * A);
    h = fmaf(dA, h, dp.y * sB[tt][n]);
    ap *= dA;
  }
  size_t off = (((size_t)b * NCH + c) * DINNER + d) * NSTATE + n;
  aprod[off] = ap;
  hacc[off] = h;
}

// ================= kernel 4: combine chunks + z-gate -> sy =================
__global__ __launch_bounds__(256) void k_combine(const float* __restrict__ aprod,
                                                 const float* __restrict__ hacc,
                                                 const float* __restrict__ dbl,
                                                 const float* __restrict__ uT,
                                                 const float* __restrict__ Dp,
                                                 const float* __restrict__ X,
                                                 const float* __restrict__ ipw,
                                                 float* __restrict__ ybuf) {
  __shared__ float sx[DMODEL];
  const int dblk = blockIdx.x & 31, b = blockIdx.x >> 5;
  const int tid = threadIdx.x;
  const int dl = tid >> 4, n = tid & 15;
  const int d = dblk * 16 + dl;
  sx[tid] = X[((size_t)b * LSEQ + LSEQ - 1) * DMODEL + tid];
  float h = 0.f;
  for (int c = 0; c < NCH; ++c) {
    size_t off = (((size_t)b * NCH + c) * DINNER + d) * NSTATE + n;
    h = fmaf(aprod[off], h, hacc[off]);
  }
  __syncthreads();
  float zp = 0.f;
  {
    const float* zr = &ipw[(size_t)(DINNER + d) * DMODEL + (n << 4)];
    #pragma unroll
    for (int q = 0; q < 4; ++q) {
      float4 w4 = *(const float4*)&zr[q << 2];
      float4 x4 = *(const float4*)&sx[(n << 4) + (q << 2)];
      zp = fmaf(w4.x, x4.x, zp); zp = fmaf(w4.y, x4.y, zp);
      zp = fmaf(w4.z, x4.z, zp); zp = fmaf(w4.w, x4.w, zp);
    }
  }
  const int btL = b * LSEQ + LSEQ - 1;
  float Cv = dbl[(size_t)btL * NPROJ + DTRANK + NSTATE + n];
  float v = h * Cv;
  #pragma unroll
  for (int off = 1; off < 16; off <<= 1) {
    v  += __shfl_xor(v, off);
    zp += __shfl_xor(zp, off);
  }
  if (n == 0) {
    float y = v + uT[(size_t)d * BL + btL] * Dp[d];
    ybuf[b * DINNER + d] = y * zp / (1.f + __expf(-zp));   // gated sy
  }
}

// ================= kernel 5: out = sy @ hwf^T + hb  (one wave per (b,t)) =================
__global__ __launch_bounds__(256) void k_out(const float* __restrict__ sy,
                                             const float* __restrict__ hwf,
                                             const float* __restrict__ hb,
                                             float* __restrict__ out) {
  const int t = blockIdx.x;            // 0..95
  const int b = threadIdx.x >> 6;      // 0..3
  const int lane = threadIdx.x & 63;
  const int k0 = lane << 3;
  const float* yr = &sy[(size_t)b * DINNER + k0];
  const float* wr = &hwf[(size_t)t * DINNER + k0];
  float4 y0 = *(const float4*)yr, y1 = *(const float4*)(yr + 4);
  float4 w0 = *(const float4*)wr, w1 = *(const float4*)(wr + 4);
  float s = y0.x * w0.x + y0.y * w0.y + y0.z * w0.z + y0.w * w0.w
          + y1.x * w1.x + y1.y * w1.y + y1.z * w1.z + y1.w * w1.w;
  #pragma unroll
  for (int off = 1; off < 64; off <<= 1) s += __shfl_xor(s, off);
  if (lane == 0) out[b * HORIZ + t] = s + hb[t];
}

extern "C" void kernel_launch(void* const* d_in, const int* in_sizes, int n_in,
                              void* d_out, int out_size, void* d_ws, size_t ws_size,
                              hipStream_t stream) {
  (void)in_sizes; (void)n_in; (void)out_size; (void)ws_size;
  const float* x    = (const float*)d_in[0];
  const float* ipw  = (const float*)d_in[1];
  const float* cw   = (const float*)d_in[2];
  const float* cb   = (const float*)d_in[3];
  const float* xpw  = (const float*)d_in[4];
  const float* dtw  = (const float*)d_in[5];
  const float* dtb  = (const float*)d_in[6];
  const float* Alog = (const float*)d_in[7];
  const float* Dp   = (const float*)d_in[8];
  const float* opw  = (const float*)d_in[9];
  const float* hw   = (const float*)d_in[10];
  const float* hb   = (const float*)d_in[11];
  float* out = (float*)d_out;
  float* ws  = (float*)d_ws;

  float* xinT  = ws;                    // 4,194,304
  float* uT    = ws + 4194304;          // 4,194,304
  float* dbl   = ws + 8388608;          //   393,216
  float* aprod = ws + 8781824;          // 1,048,576
  float* hacc  = ws + 9830400;          // 1,048,576
  float* ybuf  = ws + 10878976;         //     2,048
  float* hwf   = ws + 10881024;         //    49,152

  k_inproj<<<dim3(64, 4), 256, 0, stream>>>(x, ipw, xinT);
  k_convdbl<<<320, 256, 0, stream>>>(xinT, cw, cb, xpw, opw, hw, uT, dbl, hwf);
  k_scan<<<dim3(32, NCH, BATCH), 256, 0, stream>>>(uT, dbl, dtw, dtb, Alog, aprod, hacc);
  k_combine<<<128, 256, 0, stream>>>(aprod, hacc, dbl, uT, Dp, x, ipw, ybuf);
  k_out<<<HORIZ, 256, 0, stream>>>(ybuf, hwf, hb, out);
}